// Round 4
// baseline (296.108 us; speedup 1.0000x reference)
//
#include <hip/hip_runtime.h>
#include <hip/hip_bf16.h>

#define TT 8192
#define DD 64
#define BB 2
#define NROWS (BB * TT)  // 16384

typedef __attribute__((ext_vector_type(8))) short bf16x8;
typedef __attribute__((ext_vector_type(4))) short bf16x4;
typedef __attribute__((ext_vector_type(4))) float f32x4;

#define MFMA32 __builtin_amdgcn_mfma_f32_16x16x32_bf16

// PV matmul: legacy K=16 shape whose A-operand layout (row=lane&15,
// k=(lane>>4)*4+e) matches the S-MFMA D-layout directly -> no lane shuffle.
// (verified passing rounds 1-3)
static __device__ inline f32x4 pv_mfma16(bf16x4 a, bf16x4 b, f32x4 c) {
#if __has_builtin(__builtin_amdgcn_mfma_f32_16x16x16bf16_1k)
  return __builtin_amdgcn_mfma_f32_16x16x16bf16_1k(a, b, c, 0, 0, 0);
#else
  asm volatile("v_mfma_f32_16x16x16_bf16 %0, %1, %2, %0" : "+v"(c) : "v"(a), "v"(b));
  return c;
#endif
}

// ws layout: xb bf16[16384*64] (2MB) | xt bf16[2*64*8192] (2MB) | m fp32[16384] | mm fp32[16384]

__device__ inline unsigned short f2bf(float f) {
  unsigned int u = __float_as_uint(f);
  u += 0x7FFF + ((u >> 16) & 1);  // RNE
  return (unsigned short)(u >> 16);
}
__device__ inline float bf2f(unsigned short h) {
  return __uint_as_float(((unsigned int)h) << 16);
}
__device__ inline unsigned int pk2bf(float lo, float hi) {
  __hip_bfloat162 h = __float22bfloat162_rn(float2{lo, hi});
  union { __hip_bfloat162 h; unsigned int u; } cv;
  cv.h = h;
  return cv.u;
}

// ---------- ka: bf16 convert + m + xb + LDS-transposed xt ----------
__global__ __launch_bounds__(256) void ka_init(const float* __restrict__ x,
                                               unsigned short* __restrict__ xb,
                                               unsigned short* __restrict__ xt,
                                               float* __restrict__ m) {
  __shared__ __align__(16) unsigned short tile[64 * 72];
  int t = threadIdx.x;
  int r0 = blockIdx.x * 64;
  int rloc = t >> 2, part = t & 3;
  int r = r0 + rloc;
  const float4* px = (const float4*)(x + (size_t)r * DD + part * 16);
  unsigned short h[16];
  float msum = 0.f;
#pragma unroll
  for (int g = 0; g < 4; ++g) {
    float4 v = px[g];
    unsigned short h0 = f2bf(v.x), h1 = f2bf(v.y), h2 = f2bf(v.z), h3 = f2bf(v.w);
    h[g * 4 + 0] = h0; h[g * 4 + 1] = h1; h[g * 4 + 2] = h2; h[g * 4 + 3] = h3;
    float f0 = bf2f(h0), f1 = bf2f(h1), f2 = bf2f(h2), f3 = bf2f(h3);
    msum += f0 * f0 + f1 * f1 + f2 * f2 + f3 * f3;
  }
  uint4* xbr = (uint4*)(xb + (size_t)r * DD + part * 16);
#pragma unroll
  for (int g = 0; g < 2; ++g) {
    uint4 v;
    v.x = (unsigned int)h[g * 8 + 0] | ((unsigned int)h[g * 8 + 1] << 16);
    v.y = (unsigned int)h[g * 8 + 2] | ((unsigned int)h[g * 8 + 3] << 16);
    v.z = (unsigned int)h[g * 8 + 4] | ((unsigned int)h[g * 8 + 5] << 16);
    v.w = (unsigned int)h[g * 8 + 6] | ((unsigned int)h[g * 8 + 7] << 16);
    xbr[g] = v;
  }
#pragma unroll
  for (int k = 0; k < 16; ++k) tile[(part * 16 + k) * 72 + rloc] = h[k];
  msum += __shfl_xor(msum, 1, 64);
  msum += __shfl_xor(msum, 2, 64);
  if (part == 0) m[r] = msum;
  __syncthreads();
  int d = t >> 2, seg = t & 3;
  int b = r0 >> 13;
  int tcol = (r0 & (TT - 1)) + seg * 16;
  uint4 v0 = *(uint4*)(tile + d * 72 + seg * 16);
  uint4 v1 = *(uint4*)(tile + d * 72 + seg * 16 + 8);
  uint4* dst = (uint4*)(xt + ((size_t)b * DD + d) * TT + tcol);
  dst[0] = v0;
  dst[1] = v1;
}

// ---------- kb: mm_j = m_j + ln( sum_k exp(x_j.x_k - m_j) ) ----------
// 8 waves/block, each sweeps a private 1024-k range (32 iters of 32 k).
// B-fragments register-prefetched one iter ahead straight from global
// (L2/L1-resident); compiler-counted vmcnt; NO LDS staging, no DMA.
// (R1's design, now without the (512,4)=64-VGPR spill that killed it.)
__global__ __launch_bounds__(512, 2) void kb_l(const unsigned short* __restrict__ xq,
                                               const float* __restrict__ m,
                                               float* __restrict__ mm) {
  __shared__ float lpart[8][32];
  int w = threadIdx.x >> 6, lane = threadIdx.x & 63;
  int c = lane & 15, q = lane >> 4;
  int lid = blockIdx.x;
  int b = (lid >> 2) & 1;
  int tile = (lid & 3) | ((lid >> 3) << 2);  // 0..255
  int j0g = b * TT + tile * 32;
  bf16x8 a0[2], a1[2];
  f32x4 mv[2];
#pragma unroll
  for (int u = 0; u < 2; ++u) {
    const unsigned short* pr = xq + (size_t)(j0g + u * 16 + c) * DD + q * 8;
    a0[u] = *(const bf16x8*)pr;
    a1[u] = *(const bf16x8*)(pr + 32);
    mv[u] = *(const f32x4*)(m + j0g + u * 16 + 4 * q);
  }
  const unsigned short* xqb = xq + (size_t)(b * TT) * DD;
  const unsigned short* pb0 = xqb + (size_t)(w * 1024 + c) * DD + q * 8;
  bf16x8 b00 = *(const bf16x8*)(pb0);
  bf16x8 b01 = *(const bf16x8*)(pb0 + 32);
  bf16x8 b10 = *(const bf16x8*)(pb0 + 16 * DD);
  bf16x8 b11 = *(const bf16x8*)(pb0 + 16 * DD + 32);
  float ls[2][4] = {{0.f, 0.f, 0.f, 0.f}, {0.f, 0.f, 0.f, 0.f}};
  for (int it = 0; it < 32; ++it) {
    bf16x8 n00 = b00, n01 = b01, n10 = b10, n11 = b11;
    if (it < 31) {  // issue next-iter loads FIRST; sched_barrier pins them early
      const unsigned short* pn = pb0 + (size_t)((it + 1) * 32) * DD;
      n00 = *(const bf16x8*)(pn);
      n01 = *(const bf16x8*)(pn + 32);
      n10 = *(const bf16x8*)(pn + 16 * DD);
      n11 = *(const bf16x8*)(pn + 16 * DD + 32);
    }
    __builtin_amdgcn_sched_barrier(0);
    __builtin_amdgcn_s_setprio(1);
#pragma unroll
    for (int u = 0; u < 2; ++u) {
      f32x4 z = {0.f, 0.f, 0.f, 0.f};
      f32x4 acc0 = MFMA32(a0[u], b00, z, 0, 0, 0);
      acc0 = MFMA32(a1[u], b01, acc0, 0, 0, 0);
      f32x4 acc1 = MFMA32(a0[u], b10, z, 0, 0, 0);
      acc1 = MFMA32(a1[u], b11, acc1, 0, 0, 0);
#pragma unroll
      for (int e = 0; e < 4; ++e)
        ls[u][e] += __expf(acc0[e] - mv[u][e]) + __expf(acc1[e] - mv[u][e]);
    }
    __builtin_amdgcn_s_setprio(0);
    b00 = n00; b01 = n01; b10 = n10; b11 = n11;
  }
#pragma unroll
  for (int u = 0; u < 2; ++u)
#pragma unroll
    for (int e = 0; e < 4; ++e) {
      float v = ls[u][e];
      v += __shfl_xor(v, 1, 64);
      v += __shfl_xor(v, 2, 64);
      v += __shfl_xor(v, 4, 64);
      v += __shfl_xor(v, 8, 64);
      if (c == 0) lpart[w][u * 16 + 4 * q + e] = v;
    }
  __syncthreads();
  int t = threadIdx.x;
  if (t < 32) {
    float s = 0.f;
#pragma unroll
    for (int w2 = 0; w2 < 8; ++w2) s += lpart[w2][t];
    mm[j0g + t] = m[j0g + t] + __logf(s);
  }
}

// ---------- kc: out[b][d][i] = sum_j exp(x_j.x_i - mm_j) * x_j[d] ----------
// 8 waves/block (32-i tile), each wave sweeps a private 1024-j range in 16-j
// chunks. A, V AND mm all register-prefetched one iter ahead from global
// (L2/L1-resident) -- no main-loop LDS, no DMA, compiler-counted vmcnt.
// P feeds PV as K=16 MFMAs with zero cross-lane transform. LDS = epilogue only.
__global__ __launch_bounds__(512, 2) void kc_out(const unsigned short* __restrict__ xq,
                                                 const unsigned short* __restrict__ xt,
                                                 const float* __restrict__ mm,
                                                 float* __restrict__ out) {
  __shared__ __align__(16) unsigned short smem[36864];  // 72KB epilogue overlay (caps 2 blocks/CU)
  int w = threadIdx.x >> 6, lane = threadIdx.x & 63;
  int c = lane & 15, q = lane >> 4;
  int lid = blockIdx.x;
  int b = (lid >> 2) & 1;
  int tile = (lid & 3) | ((lid >> 3) << 2);
  int i0 = tile * 32;
  bf16x8 bq0[2], bq1[2];
#pragma unroll
  for (int u = 0; u < 2; ++u) {
    const unsigned short* pr = xq + (size_t)(b * TT + i0 + u * 16 + c) * DD + q * 8;
    bq0[u] = *(const bf16x8*)pr;
    bq1[u] = *(const bf16x8*)(pr + 32);
  }
  f32x4 o[2][4];
#pragma unroll
  for (int u = 0; u < 2; ++u)
#pragma unroll
    for (int nt = 0; nt < 4; ++nt) o[u][nt] = (f32x4){0.f, 0.f, 0.f, 0.f};

  const unsigned short* xqb = xq + (size_t)(b * TT) * DD;
  const unsigned short* xtb = xt + (size_t)b * DD * TT;
  const float* mmb = mm + b * TT;
  int jq0 = w * 1024;
  const unsigned short* pa0 = xqb + (size_t)(jq0 + c) * DD + q * 8;   // A: row jq0+c, d-slice q*8
  const unsigned short* pv0 = xtb + (size_t)c * TT + jq0 + 4 * q;     // V: row d=c(+nt*16), col jq0+4q

  // iter-0 preload
  bf16x8 ca0 = *(const bf16x8*)(pa0);
  bf16x8 ca1 = *(const bf16x8*)(pa0 + 32);
  bf16x4 cv0 = *(const bf16x4*)(pv0);
  bf16x4 cv1 = *(const bf16x4*)(pv0 + 16 * TT);
  bf16x4 cv2 = *(const bf16x4*)(pv0 + 32 * TT);
  bf16x4 cv3 = *(const bf16x4*)(pv0 + 48 * TT);
  f32x4 cmm = *(const f32x4*)(mmb + jq0 + 4 * q);

  for (int it = 0; it < 64; ++it) {
    bf16x8 na0 = ca0, na1 = ca1;
    bf16x4 nv0 = cv0, nv1 = cv1, nv2 = cv2, nv3 = cv3;
    f32x4 nmm = cmm;
    if (it < 63) {  // issue next-iter loads FIRST; sched_barrier pins them early
      const unsigned short* pan = pa0 + (size_t)((it + 1) * 16) * DD;
      const unsigned short* pvn = pv0 + (it + 1) * 16;
      na0 = *(const bf16x8*)(pan);
      na1 = *(const bf16x8*)(pan + 32);
      nv0 = *(const bf16x4*)(pvn);
      nv1 = *(const bf16x4*)(pvn + 16 * TT);
      nv2 = *(const bf16x4*)(pvn + 32 * TT);
      nv3 = *(const bf16x4*)(pvn + 48 * TT);
      nmm = *(const f32x4*)(mmb + jq0 + (it + 1) * 16 + 4 * q);
    }
    __builtin_amdgcn_sched_barrier(0);
    __builtin_amdgcn_s_setprio(1);
#pragma unroll
    for (int u = 0; u < 2; ++u) {
      f32x4 z = {0.f, 0.f, 0.f, 0.f};
      f32x4 s0 = MFMA32(ca0, bq0[u], z, 0, 0, 0);
      s0 = MFMA32(ca1, bq1[u], s0, 0, 0, 0);
      float w00 = __expf(s0[0] - cmm[0]);
      float w01 = __expf(s0[1] - cmm[1]);
      float w02 = __expf(s0[2] - cmm[2]);
      float w03 = __expf(s0[3] - cmm[3]);
      union { unsigned int uu[2]; bf16x4 v; } plo;
      plo.uu[0] = pk2bf(w00, w01);
      plo.uu[1] = pk2bf(w02, w03);
      o[u][0] = pv_mfma16(plo.v, cv0, o[u][0]);
      o[u][1] = pv_mfma16(plo.v, cv1, o[u][1]);
      o[u][2] = pv_mfma16(plo.v, cv2, o[u][2]);
      o[u][3] = pv_mfma16(plo.v, cv3, o[u][3]);
    }
    __builtin_amdgcn_s_setprio(0);
    ca0 = na0; ca1 = na1;
    cv0 = nv0; cv1 = nv1; cv2 = nv2; cv3 = nv3;
    cmm = nmm;
  }
  // cross-wave O reduce: Olds[w][d 64][pitch 36 fp32]
  __syncthreads();
  float* ow = (float*)smem + w * 2304;
#pragma unroll
  for (int u = 0; u < 2; ++u)
#pragma unroll
    for (int nt = 0; nt < 4; ++nt)
      *(f32x4*)(ow + (nt * 16 + c) * 36 + u * 16 + 4 * q) = o[u][nt];
  __syncthreads();
  int t = threadIdx.x, d = t & 63, g = t >> 6;  // g = 0..7 -> 4 i's each
  const float* sbase = (const float*)smem;
  f32x4 sA = {0.f, 0.f, 0.f, 0.f};
#pragma unroll
  for (int w2 = 0; w2 < 8; ++w2)
    sA += *(const f32x4*)(sbase + w2 * 2304 + d * 36 + g * 4);
  *(f32x4*)(out + ((size_t)(b * DD + d)) * TT + i0 + g * 4) = sA;
}

extern "C" void kernel_launch(void* const* d_in, const int* in_sizes, int n_in,
                              void* d_out, int out_size, void* d_ws, size_t ws_size,
                              hipStream_t stream) {
  const float* x = (const float*)d_in[0];
  float* out = (float*)d_out;
  unsigned short* xb = (unsigned short*)d_ws;
  unsigned short* xt = xb + (size_t)NROWS * DD;
  float* m = (float*)(xt + (size_t)NROWS * DD);
  float* mmv = m + NROWS;

  ka_init<<<NROWS / 64, 256, 0, stream>>>(x, xb, xt, m);
  kb_l<<<512, 512, 0, stream>>>(xb, m, mmv);
  kc_out<<<512, 512, 0, stream>>>(xb, xt, mmv, out);
}

// Round 5
// 267.995 us; speedup vs baseline: 1.1049x; 1.1049x over previous
//
#include <hip/hip_runtime.h>
#include <hip/hip_bf16.h>

#define TT 8192
#define DD 64
#define BB 2
#define NROWS (BB * TT)  // 16384

typedef __attribute__((ext_vector_type(8))) short bf16x8;
typedef __attribute__((ext_vector_type(4))) short bf16x4;
typedef __attribute__((ext_vector_type(4))) float f32x4;

#define MFMA32 __builtin_amdgcn_mfma_f32_16x16x32_bf16

// PV matmul: legacy K=16 shape whose A-operand layout (row=lane&15,
// k=(lane>>4)*4+e) matches the S-MFMA D-layout directly -> no lane shuffle.
// (verified passing rounds 1-4)
static __device__ inline f32x4 pv_mfma16(bf16x4 a, bf16x4 b, f32x4 c) {
#if __has_builtin(__builtin_amdgcn_mfma_f32_16x16x16bf16_1k)
  return __builtin_amdgcn_mfma_f32_16x16x16bf16_1k(a, b, c, 0, 0, 0);
#else
  asm volatile("v_mfma_f32_16x16x16_bf16 %0, %1, %2, %0" : "+v"(c) : "v"(a), "v"(b));
  return c;
#endif
}

typedef __attribute__((address_space(1))) const unsigned int gu32;
typedef __attribute__((address_space(3))) unsigned int lu32;

// async global->LDS, 16B per lane; LDS dest = wave-uniform base + lane*16
__device__ inline void gld_lds16(const unsigned short* g, unsigned short* l) {
  __builtin_amdgcn_global_load_lds((gu32*)g, (lu32*)l, 16, 0, 0);
}

// ws layout: xb bf16[16384*64] (2MB) | xt bf16[2*64*8192] (2MB) | m fp32[16384] | mm fp32[16384]

__device__ inline unsigned short f2bf(float f) {
  unsigned int u = __float_as_uint(f);
  u += 0x7FFF + ((u >> 16) & 1);  // RNE
  return (unsigned short)(u >> 16);
}
__device__ inline float bf2f(unsigned short h) {
  return __uint_as_float(((unsigned int)h) << 16);
}
__device__ inline unsigned int pk2bf(float lo, float hi) {
  __hip_bfloat162 h = __float22bfloat162_rn(float2{lo, hi});
  union { __hip_bfloat162 h; unsigned int u; } cv;
  cv.h = h;
  return cv.u;
}

// ---------- ka: bf16 convert + m + xb + LDS-transposed xt ----------
__global__ __launch_bounds__(256) void ka_init(const float* __restrict__ x,
                                               unsigned short* __restrict__ xb,
                                               unsigned short* __restrict__ xt,
                                               float* __restrict__ m) {
  __shared__ __align__(16) unsigned short tile[64 * 72];
  int t = threadIdx.x;
  int r0 = blockIdx.x * 64;
  int rloc = t >> 2, part = t & 3;
  int r = r0 + rloc;
  const float4* px = (const float4*)(x + (size_t)r * DD + part * 16);
  unsigned short h[16];
  float msum = 0.f;
#pragma unroll
  for (int g = 0; g < 4; ++g) {
    float4 v = px[g];
    unsigned short h0 = f2bf(v.x), h1 = f2bf(v.y), h2 = f2bf(v.z), h3 = f2bf(v.w);
    h[g * 4 + 0] = h0; h[g * 4 + 1] = h1; h[g * 4 + 2] = h2; h[g * 4 + 3] = h3;
    float f0 = bf2f(h0), f1 = bf2f(h1), f2 = bf2f(h2), f3 = bf2f(h3);
    msum += f0 * f0 + f1 * f1 + f2 * f2 + f3 * f3;
  }
  uint4* xbr = (uint4*)(xb + (size_t)r * DD + part * 16);
#pragma unroll
  for (int g = 0; g < 2; ++g) {
    uint4 v;
    v.x = (unsigned int)h[g * 8 + 0] | ((unsigned int)h[g * 8 + 1] << 16);
    v.y = (unsigned int)h[g * 8 + 2] | ((unsigned int)h[g * 8 + 3] << 16);
    v.z = (unsigned int)h[g * 8 + 4] | ((unsigned int)h[g * 8 + 5] << 16);
    v.w = (unsigned int)h[g * 8 + 6] | ((unsigned int)h[g * 8 + 7] << 16);
    xbr[g] = v;
  }
#pragma unroll
  for (int k = 0; k < 16; ++k) tile[(part * 16 + k) * 72 + rloc] = h[k];
  msum += __shfl_xor(msum, 1, 64);
  msum += __shfl_xor(msum, 2, 64);
  if (part == 0) m[r] = msum;
  __syncthreads();
  int d = t >> 2, seg = t & 3;
  int b = r0 >> 13;
  int tcol = (r0 & (TT - 1)) + seg * 16;
  uint4 v0 = *(uint4*)(tile + d * 72 + seg * 16);
  uint4 v1 = *(uint4*)(tile + d * 72 + seg * 16 + 8);
  uint4* dst = (uint4*)(xt + ((size_t)b * DD + d) * TT + tcol);
  dst[0] = v0;
  dst[1] = v1;
}

// ---------- kb: mm_j = m_j + ln( sum_k exp(x_j.x_k - m_j) ) ----------
// BLOCK-SHARED staging: 256 blocks, each owns a 64-j tile and sweeps the FULL
// 8192-k range of its batch in shared 128-k slabs (16KB, double-buffered).
// 8 waves = 2 j-groups x 4 k-groups consume the shared slab -> per-CU DMA
// bytes drop 2x vs R3 (the measured bottleneck). Also pre-zeroes `out` for
// kc's atomic partial sums.
__global__ __launch_bounds__(512, 2) void kb_l(const unsigned short* __restrict__ xq,
                                               const float* __restrict__ m,
                                               float* __restrict__ mm,
                                               float* __restrict__ outz) {
  __shared__ __align__(16) unsigned short kslab[2][128 * 64];  // 32KB
  __shared__ float lpart[8][32];
  // zero out[] (1M floats over 256 blocks x 512 thr x 8)
  {
    size_t zb = ((size_t)blockIdx.x * 512 + threadIdx.x) * 8;
    *(f32x4*)(outz + zb) = (f32x4){0.f, 0.f, 0.f, 0.f};
    *(f32x4*)(outz + zb + 4) = (f32x4){0.f, 0.f, 0.f, 0.f};
  }
  int w = threadIdx.x >> 6, lane = threadIdx.x & 63;
  int c = lane & 15, q = lane >> 4;
  int lid = blockIdx.x;          // 0..255
  int bb = lid >> 7;             // batch
  int j0g = lid * 64;            // global j-row base (includes batch)
  int wj2 = w >> 2, wk = w & 3;  // wave's j-group (32 rows) and k-group (32 cols)
  bf16x8 a0[2], a1[2];
  f32x4 mv[2];
#pragma unroll
  for (int u = 0; u < 2; ++u) {
    const unsigned short* pr = xq + (size_t)(j0g + wj2 * 32 + u * 16 + c) * DD + q * 8;
    a0[u] = *(const bf16x8*)pr;
    a1[u] = *(const bf16x8*)(pr + 32);
    mv[u] = *(const f32x4*)(m + j0g + wj2 * 32 + u * 16 + 4 * q);
  }
  const unsigned short* xqb = xq + (size_t)(bb * TT) * DD;
  int srow = lane >> 3;
  int sch = (lane & 7) ^ srow;   // 16B source-granule XOR swizzle (row&7)
  auto stage = [&](int buf, int kc) {
#pragma unroll
    for (int t = 0; t < 2; ++t)
      gld_lds16(xqb + (size_t)(kc + w * 16 + t * 8 + srow) * DD + sch * 8,
                &kslab[buf][0] + w * 1024 + t * 512);
  };
  stage(0, 0);
  asm volatile("s_waitcnt vmcnt(0)" ::: "memory");
  __syncthreads();
  float ls[2][4] = {{0.f, 0.f, 0.f, 0.f}, {0.f, 0.f, 0.f, 0.f}};
  int o1 = (q ^ (c & 7)) * 8, o2 = ((q | 4) ^ (c & 7)) * 8;
  for (int ks = 0; ks < 64; ++ks) {
    if (ks < 63) stage((ks & 1) ^ 1, (ks + 1) * 128);
    const unsigned short* kp = &kslab[ks & 1][0] + wk * 2048;  // wave's 32-k piece
    bf16x8 b00 = *(const bf16x8*)(kp + c * 64 + o1);
    bf16x8 b01 = *(const bf16x8*)(kp + c * 64 + o2);
    bf16x8 b10 = *(const bf16x8*)(kp + (c + 16) * 64 + o1);
    bf16x8 b11 = *(const bf16x8*)(kp + (c + 16) * 64 + o2);
    __builtin_amdgcn_s_setprio(1);
#pragma unroll
    for (int u = 0; u < 2; ++u) {
      f32x4 z = {0.f, 0.f, 0.f, 0.f};
      f32x4 acc0 = MFMA32(a0[u], b00, z, 0, 0, 0);
      acc0 = MFMA32(a1[u], b01, acc0, 0, 0, 0);
      f32x4 acc1 = MFMA32(a0[u], b10, z, 0, 0, 0);
      acc1 = MFMA32(a1[u], b11, acc1, 0, 0, 0);
#pragma unroll
      for (int e = 0; e < 4; ++e)
        ls[u][e] += __expf(acc0[e] - mv[u][e]) + __expf(acc1[e] - mv[u][e]);
    }
    __builtin_amdgcn_s_setprio(0);
    asm volatile("s_waitcnt vmcnt(0)" ::: "memory");
    __syncthreads();
  }
#pragma unroll
  for (int u = 0; u < 2; ++u)
#pragma unroll
    for (int e = 0; e < 4; ++e) {
      float v = ls[u][e];
      v += __shfl_xor(v, 1, 64);
      v += __shfl_xor(v, 2, 64);
      v += __shfl_xor(v, 4, 64);
      v += __shfl_xor(v, 8, 64);
      if (c == 0) lpart[w][u * 16 + 4 * q + e] = v;
    }
  __syncthreads();
  int t = threadIdx.x;
  if (t < 64) {
    int jg = t >> 5;  // which wj2 group
    float s = 0.f;
#pragma unroll
    for (int k3 = 0; k3 < 4; ++k3) s += lpart[jg * 4 + k3][t & 31];
    mm[j0g + t] = m[j0g + t] + __logf(s);
  }
}

// ---------- kc: out[b][d][i] += sum_j exp(x_j.x_i - mm_j) * x_j[d] ----------
// BLOCK-SHARED staging: 256 blocks = 128 i-tiles(128 rows) x 2 j-halves.
// Per iter: shared 64-j slab (A rows 8KB + V[d][j] 8KB), double-buffered,
// staged cooperatively (2 DMAs/wave); 8 waves = 4 i-groups x 2 j-groups.
// Per-CU DMA bytes drop 4x vs R3 (the measured bottleneck). j-halves merge
// into out via atomicAdd (pre-zeroed by kb).
__global__ __launch_bounds__(512, 2) void kc_out(const unsigned short* __restrict__ xq,
                                                 const unsigned short* __restrict__ xt,
                                                 const float* __restrict__ mm,
                                                 float* __restrict__ out) {
  __shared__ __align__(16) unsigned short smem[36864];  // A 2x8KB | V 2x8KB | 72KB epilogue overlay
  int w = threadIdx.x >> 6, lane = threadIdx.x & 63;
  int c = lane & 15, q = lane >> 4;
  int lid = blockIdx.x;
  int it = lid >> 1, jh = lid & 1;
  int bb = it >> 6;
  int i0 = (it & 63) * 128;
  int wi = w >> 1, wj = w & 1;
  bf16x8 bq0[2], bq1[2];
#pragma unroll
  for (int u = 0; u < 2; ++u) {
    const unsigned short* pr = xq + (size_t)(bb * TT + i0 + wi * 32 + u * 16 + c) * DD + q * 8;
    bq0[u] = *(const bf16x8*)pr;
    bq1[u] = *(const bf16x8*)(pr + 32);
  }
  f32x4 o[2][4];
#pragma unroll
  for (int u = 0; u < 2; ++u)
#pragma unroll
    for (int nt = 0; nt < 4; ++nt) o[u][nt] = (f32x4){0.f, 0.f, 0.f, 0.f};

  const unsigned short* xqb = xq + (size_t)(bb * TT) * DD;
  const unsigned short* xtb = xt + (size_t)bb * DD * TT;
  const float* mmb = mm + bb * TT;
  int j0 = jh * 4096;
  unsigned short* asl = smem;          // A slabs: [buf][64 rows][64 shorts]
  unsigned short* vsl = smem + 8192;   // V slabs: [buf][64 d-rows][64 shorts]
  int srow = lane >> 3;
  int sch = (lane & 7) ^ srow;         // 16B source-granule XOR swizzle (row&7)
  auto stage = [&](int buf, int jc) {
    gld_lds16(xqb + (size_t)(jc + w * 8 + srow) * DD + sch * 8,
              asl + buf * 4096 + w * 512);
    gld_lds16(xtb + (size_t)(w * 8 + srow) * TT + jc + sch * 8,
              vsl + buf * 4096 + w * 512);
  };
  stage(0, j0);
  // mm prefetch (wave's 32-j piece: jj=0 and jj=1 16-row groups)
  f32x4 cmm0 = *(const f32x4*)(mmb + j0 + wj * 32 + 4 * q);
  f32x4 cmm1 = *(const f32x4*)(mmb + j0 + wj * 32 + 16 + 4 * q);
  asm volatile("s_waitcnt vmcnt(0)" ::: "memory");
  __syncthreads();
  int o1 = (q ^ (c & 7)) * 8, o2 = ((q | 4) ^ (c & 7)) * 8;

  for (int js = 0; js < 64; ++js) {
    int jc = j0 + js * 64;
    f32x4 nmm0 = cmm0, nmm1 = cmm1;
    if (js < 63) {
      stage((js & 1) ^ 1, jc + 64);
      nmm0 = *(const f32x4*)(mmb + jc + 64 + wj * 32 + 4 * q);
      nmm1 = *(const f32x4*)(mmb + jc + 64 + wj * 32 + 16 + 4 * q);
    }
    const unsigned short* ap = asl + (js & 1) * 4096 + wj * 2048;  // wave's 32-j rows
    const unsigned short* vp = vsl + (js & 1) * 4096;
    bf16x8 a00 = *(const bf16x8*)(ap + c * 64 + o1);          // jj=0 rows
    bf16x8 a01 = *(const bf16x8*)(ap + c * 64 + o2);
    bf16x8 a10 = *(const bf16x8*)(ap + (c + 16) * 64 + o1);   // jj=1 rows
    bf16x8 a11 = *(const bf16x8*)(ap + (c + 16) * 64 + o2);
    // V frags: bv[jj][nt] = x[j = jc + wj*32 + jj*16 + 4q+e][d = nt*16+c]
    bf16x4 bv[2][4];
#pragma unroll
    for (int jj = 0; jj < 2; ++jj)
#pragma unroll
      for (int nt = 0; nt < 4; ++nt) {
        int pg = (wj * 4 + jj * 2 + (q >> 1)) ^ (c & 7);
        bv[jj][nt] = *(const bf16x4*)(vp + (nt * 16 + c) * 64 + pg * 8 + (q & 1) * 4);
      }
    __builtin_amdgcn_s_setprio(1);
#pragma unroll
    for (int u = 0; u < 2; ++u) {
      f32x4 z = {0.f, 0.f, 0.f, 0.f};
      f32x4 s0 = MFMA32(a00, bq0[u], z, 0, 0, 0);
      s0 = MFMA32(a01, bq1[u], s0, 0, 0, 0);
      f32x4 s1 = MFMA32(a10, bq0[u], z, 0, 0, 0);
      s1 = MFMA32(a11, bq1[u], s1, 0, 0, 0);
      float w00 = __expf(s0[0] - cmm0[0]);
      float w01 = __expf(s0[1] - cmm0[1]);
      float w02 = __expf(s0[2] - cmm0[2]);
      float w03 = __expf(s0[3] - cmm0[3]);
      float w10 = __expf(s1[0] - cmm1[0]);
      float w11 = __expf(s1[1] - cmm1[1]);
      float w12 = __expf(s1[2] - cmm1[2]);
      float w13 = __expf(s1[3] - cmm1[3]);
      union { unsigned int uu[2]; bf16x4 v; } pA, pB;
      pA.uu[0] = pk2bf(w00, w01);
      pA.uu[1] = pk2bf(w02, w03);
      pB.uu[0] = pk2bf(w10, w11);
      pB.uu[1] = pk2bf(w12, w13);
#pragma unroll
      for (int nt = 0; nt < 4; ++nt) {
        o[u][nt] = pv_mfma16(pA.v, bv[0][nt], o[u][nt]);
        o[u][nt] = pv_mfma16(pB.v, bv[1][nt], o[u][nt]);
      }
    }
    __builtin_amdgcn_s_setprio(0);
    cmm0 = nmm0;
    cmm1 = nmm1;
    asm volatile("s_waitcnt vmcnt(0)" ::: "memory");
    __syncthreads();
  }
  // cross-wave O merge over wj pairs: Olds[w][d 64][pitch 36 fp32]
  float* ow = (float*)smem + w * 2304;
#pragma unroll
  for (int u = 0; u < 2; ++u)
#pragma unroll
    for (int nt = 0; nt < 4; ++nt)
      *(f32x4*)(ow + (nt * 16 + c) * 36 + u * 16 + 4 * q) = o[u][nt];
  __syncthreads();
  int t = threadIdx.x, d = t & 63, g = t >> 6;  // g = 0..7 -> 4 i's per wi-group
  const float* sbase = (const float*)smem;
#pragma unroll
  for (int wi2 = 0; wi2 < 4; ++wi2) {
    f32x4 sA = *(const f32x4*)(sbase + (wi2 * 2 + 0) * 2304 + d * 36 + g * 4);
    sA += *(const f32x4*)(sbase + (wi2 * 2 + 1) * 2304 + d * 36 + g * 4);
    size_t ob = ((size_t)(bb * DD + d)) * TT + i0 + wi2 * 32 + g * 4;
    atomicAdd(out + ob + 0, sA[0]);
    atomicAdd(out + ob + 1, sA[1]);
    atomicAdd(out + ob + 2, sA[2]);
    atomicAdd(out + ob + 3, sA[3]);
  }
}

extern "C" void kernel_launch(void* const* d_in, const int* in_sizes, int n_in,
                              void* d_out, int out_size, void* d_ws, size_t ws_size,
                              hipStream_t stream) {
  const float* x = (const float*)d_in[0];
  float* out = (float*)d_out;
  unsigned short* xb = (unsigned short*)d_ws;
  unsigned short* xt = xb + (size_t)NROWS * DD;
  float* m = (float*)(xt + (size_t)NROWS * DD);
  float* mmv = m + NROWS;

  ka_init<<<NROWS / 64, 256, 0, stream>>>(x, xb, xt, m);
  kb_l<<<256, 512, 0, stream>>>(xb, m, mmv, out);
  kc_out<<<256, 512, 0, stream>>>(xb, xt, mmv, out);
}

// Round 6
// 226.043 us; speedup vs baseline: 1.3100x; 1.1856x over previous
//
#include <hip/hip_runtime.h>
#include <hip/hip_bf16.h>

#define TT 8192
#define DD 64
#define BB 2
#define NROWS (BB * TT)  // 16384

typedef __attribute__((ext_vector_type(8))) short bf16x8;
typedef __attribute__((ext_vector_type(4))) short bf16x4;
typedef __attribute__((ext_vector_type(4))) float f32x4;

#define MFMA32 __builtin_amdgcn_mfma_f32_16x16x32_bf16

// PV matmul: legacy K=16 shape whose A-operand layout (row=lane&15,
// k=(lane>>4)*4+e) matches the S-MFMA D-layout directly -> no lane shuffle.
// (verified passing rounds 1-5)
static __device__ inline f32x4 pv_mfma16(bf16x4 a, bf16x4 b, f32x4 c) {
#if __has_builtin(__builtin_amdgcn_mfma_f32_16x16x16bf16_1k)
  return __builtin_amdgcn_mfma_f32_16x16x16bf16_1k(a, b, c, 0, 0, 0);
#else
  asm volatile("v_mfma_f32_16x16x16_bf16 %0, %1, %2, %0" : "+v"(c) : "v"(a), "v"(b));
  return c;
#endif
}

typedef __attribute__((address_space(1))) const unsigned int gu32;
typedef __attribute__((address_space(3))) unsigned int lu32;

// async global->LDS, 16B per lane; LDS dest = wave-uniform base + lane*16
__device__ inline void gld_lds16(const unsigned short* g, unsigned short* l) {
  __builtin_amdgcn_global_load_lds((gu32*)g, (lu32*)l, 16, 0, 0);
}

// ws layout: xb bf16[16384*64] (2MB) | xt bf16[2*64*8192] (2MB) | m fp32[16384] | mm fp32[16384]

__device__ inline unsigned short f2bf(float f) {
  unsigned int u = __float_as_uint(f);
  u += 0x7FFF + ((u >> 16) & 1);  // RNE
  return (unsigned short)(u >> 16);
}
__device__ inline float bf2f(unsigned short h) {
  return __uint_as_float(((unsigned int)h) << 16);
}
__device__ inline unsigned int pk2bf(float lo, float hi) {
  __hip_bfloat162 h = __float22bfloat162_rn(float2{lo, hi});
  union { __hip_bfloat162 h; unsigned int u; } cv;
  cv.h = h;
  return cv.u;
}

// ---------- ka: bf16 convert + m + xb + LDS-transposed xt ----------
__global__ __launch_bounds__(256) void ka_init(const float* __restrict__ x,
                                               unsigned short* __restrict__ xb,
                                               unsigned short* __restrict__ xt,
                                               float* __restrict__ m) {
  __shared__ __align__(16) unsigned short tile[64 * 72];
  int t = threadIdx.x;
  int r0 = blockIdx.x * 64;
  int rloc = t >> 2, part = t & 3;
  int r = r0 + rloc;
  const float4* px = (const float4*)(x + (size_t)r * DD + part * 16);
  unsigned short h[16];
  float msum = 0.f;
#pragma unroll
  for (int g = 0; g < 4; ++g) {
    float4 v = px[g];
    unsigned short h0 = f2bf(v.x), h1 = f2bf(v.y), h2 = f2bf(v.z), h3 = f2bf(v.w);
    h[g * 4 + 0] = h0; h[g * 4 + 1] = h1; h[g * 4 + 2] = h2; h[g * 4 + 3] = h3;
    float f0 = bf2f(h0), f1 = bf2f(h1), f2 = bf2f(h2), f3 = bf2f(h3);
    msum += f0 * f0 + f1 * f1 + f2 * f2 + f3 * f3;
  }
  uint4* xbr = (uint4*)(xb + (size_t)r * DD + part * 16);
#pragma unroll
  for (int g = 0; g < 2; ++g) {
    uint4 v;
    v.x = (unsigned int)h[g * 8 + 0] | ((unsigned int)h[g * 8 + 1] << 16);
    v.y = (unsigned int)h[g * 8 + 2] | ((unsigned int)h[g * 8 + 3] << 16);
    v.z = (unsigned int)h[g * 8 + 4] | ((unsigned int)h[g * 8 + 5] << 16);
    v.w = (unsigned int)h[g * 8 + 6] | ((unsigned int)h[g * 8 + 7] << 16);
    xbr[g] = v;
  }
#pragma unroll
  for (int k = 0; k < 16; ++k) tile[(part * 16 + k) * 72 + rloc] = h[k];
  msum += __shfl_xor(msum, 1, 64);
  msum += __shfl_xor(msum, 2, 64);
  if (part == 0) m[r] = msum;
  __syncthreads();
  int d = t >> 2, seg = t & 3;
  int b = r0 >> 13;
  int tcol = (r0 & (TT - 1)) + seg * 16;
  uint4 v0 = *(uint4*)(tile + d * 72 + seg * 16);
  uint4 v1 = *(uint4*)(tile + d * 72 + seg * 16 + 8);
  uint4* dst = (uint4*)(xt + ((size_t)b * DD + d) * TT + tcol);
  dst[0] = v0;
  dst[1] = v1;
}

// ---------- kb: mm_j = m_j + ln( sum_k exp(x_j.x_k - m_j) ) ----------
// R3 skeleton, depth-3 DMA pipeline: 8 waves/block, each sweeps a private
// 1024-k range in 64 iters of 16-k; 4 LDS buffers/wave; issue stage t+3,
// counted vmcnt(6) so 3 stages (6 DMAs) stay in flight. No barriers in loop.
__global__ __launch_bounds__(512, 2) void kb_l(const unsigned short* __restrict__ xq,
                                               const float* __restrict__ m,
                                               float* __restrict__ mm) {
  __shared__ __align__(16) unsigned short kslab[8][4][1024];  // 64KB
  __shared__ float lpart[8][32];
  int w = threadIdx.x >> 6, lane = threadIdx.x & 63;
  int c = lane & 15, q = lane >> 4;
  int lid = blockIdx.x;
  int b = (lid >> 2) & 1;
  int tile = (lid & 3) | ((lid >> 3) << 2);  // 0..255
  int j0g = b * TT + tile * 32;
  bf16x8 a0[2], a1[2];
  f32x4 mv[2];
#pragma unroll
  for (int u = 0; u < 2; ++u) {
    const unsigned short* pr = xq + (size_t)(j0g + u * 16 + c) * DD + q * 8;
    a0[u] = *(const bf16x8*)pr;
    a1[u] = *(const bf16x8*)(pr + 32);
    mv[u] = *(const f32x4*)(m + j0g + u * 16 + 4 * q);
  }
  const unsigned short* xqb = xq + (size_t)(b * TT) * DD;
  int k0 = w * 1024;
  int srow = lane >> 3;
  int sch = (lane & 7) ^ srow;  // 16B source-granule XOR swizzle (verified R3)
  unsigned short* sb = &kslab[w][0][0];
  float ls[2][4] = {{0.f, 0.f, 0.f, 0.f}, {0.f, 0.f, 0.f, 0.f}};
  int o1 = (q ^ (c & 7)) * 8, o2 = ((q | 4) ^ (c & 7)) * 8;

#define KB_ISSUE(S, kn) do { \
    __builtin_amdgcn_sched_barrier(0); \
    gld_lds16(xqb + (size_t)((kn) + srow) * DD + sch * 8, sb + (S) * 1024); \
    gld_lds16(xqb + (size_t)((kn) + 8 + srow) * DD + sch * 8, sb + (S) * 1024 + 512); \
    __builtin_amdgcn_sched_barrier(0); \
  } while (0)
#define KB_WAIT(N) do { \
    asm volatile("s_waitcnt vmcnt(" #N ")" ::: "memory"); \
    __builtin_amdgcn_sched_barrier(0); \
  } while (0)
#define KB_BODY(S) do { \
    const unsigned short* kp = sb + (S) * 1024; \
    bf16x8 b00 = *(const bf16x8*)(kp + c * 64 + o1); \
    bf16x8 b01 = *(const bf16x8*)(kp + c * 64 + o2); \
    __builtin_amdgcn_s_setprio(1); \
    _Pragma("unroll") for (int u = 0; u < 2; ++u) { \
      f32x4 z = {0.f, 0.f, 0.f, 0.f}; \
      f32x4 acc0 = MFMA32(a0[u], b00, z, 0, 0, 0); \
      acc0 = MFMA32(a1[u], b01, acc0, 0, 0, 0); \
      _Pragma("unroll") for (int e = 0; e < 4; ++e) \
        ls[u][e] += __expf(acc0[e] - mv[u][e]); \
    } \
    __builtin_amdgcn_s_setprio(0); \
  } while (0)

  KB_ISSUE(0, k0);
  KB_ISSUE(1, k0 + 16);
  KB_ISSUE(2, k0 + 32);
  for (int g = 0; g < 15; ++g) {
    int kb2 = k0 + g * 64;
    KB_ISSUE(3, kb2 + 48); KB_WAIT(6); KB_BODY(0);
    KB_ISSUE(0, kb2 + 64); KB_WAIT(6); KB_BODY(1);
    KB_ISSUE(1, kb2 + 80); KB_WAIT(6); KB_BODY(2);
    KB_ISSUE(2, kb2 + 96); KB_WAIT(6); KB_BODY(3);
  }
  KB_ISSUE(3, k0 + 1008); KB_WAIT(6); KB_BODY(0);
  KB_WAIT(4); KB_BODY(1);
  KB_WAIT(2); KB_BODY(2);
  KB_WAIT(0); KB_BODY(3);

#pragma unroll
  for (int u = 0; u < 2; ++u)
#pragma unroll
    for (int e = 0; e < 4; ++e) {
      float v = ls[u][e];
      v += __shfl_xor(v, 1, 64);
      v += __shfl_xor(v, 2, 64);
      v += __shfl_xor(v, 4, 64);
      v += __shfl_xor(v, 8, 64);
      if (c == 0) lpart[w][u * 16 + 4 * q + e] = v;
    }
  __syncthreads();
  int t = threadIdx.x;
  if (t < 32) {
    float s = 0.f;
#pragma unroll
    for (int w2 = 0; w2 < 8; ++w2) s += lpart[w2][t];
    mm[j0g + t] = m[j0g + t] + __logf(s);
  }
}

// ---------- kc: out[b][d][i] = sum_j exp(x_j.x_i - mm_j) * x_j[d] ----------
// R3 skeleton, depth-3 pipeline: 8 waves/block (32-i tile), private 1024-j
// range in 64 iters of 16-j. A: 4 LDS-DMA buffers/wave. V+mm: 4-slot register
// prefetch via inline-asm global loads (compiler cannot sink them). Fixed
// per-iter issue order [2 DMA][5 asm] = 7 -> consume with vmcnt(21) = 3 iters
// in flight. No barriers in the main loop; LDS epilogue overlay unchanged.
__global__ __launch_bounds__(512, 2) void kc_out(const unsigned short* __restrict__ xq,
                                                 const unsigned short* __restrict__ xt,
                                                 const float* __restrict__ mm,
                                                 float* __restrict__ out) {
  __shared__ __align__(16) unsigned short smem[36864];  // A 8x(4x2KB)=64KB | 72KB epilogue overlay
  int w = threadIdx.x >> 6, lane = threadIdx.x & 63;
  int c = lane & 15, q = lane >> 4;
  int lid = blockIdx.x;
  int b = (lid >> 2) & 1;
  int tile = (lid & 3) | ((lid >> 3) << 2);
  int i0 = tile * 32;
  bf16x8 bq0[2], bq1[2];
#pragma unroll
  for (int u = 0; u < 2; ++u) {
    const unsigned short* pr = xq + (size_t)(b * TT + i0 + u * 16 + c) * DD + q * 8;
    bq0[u] = *(const bf16x8*)pr;
    bq1[u] = *(const bf16x8*)(pr + 32);
  }
  f32x4 o[2][4];
#pragma unroll
  for (int u = 0; u < 2; ++u)
#pragma unroll
    for (int nt = 0; nt < 4; ++nt) o[u][nt] = (f32x4){0.f, 0.f, 0.f, 0.f};

  const unsigned short* xqb = xq + (size_t)(b * TT) * DD;
  const unsigned short* xtb = xt + (size_t)b * DD * TT;
  const float* mmb = mm + b * TT;
  int jq0 = w * 1024;
  unsigned short* asb = smem + w * 4096;  // 4 bufs x 1024 shorts
  int srow = lane >> 3;
  int sch = (lane & 7) ^ srow;            // 16B source-granule XOR swizzle (verified R3)
  const unsigned short* pv0 = xtb + (size_t)c * TT + 4 * q;  // V: d-row c(+nt*16), col 4q
  int o1 = (q ^ (c & 7)) * 8, o2 = ((q | 4) ^ (c & 7)) * 8;

  // 4-slot register prefetch state for V (4x8B) and mm (16B)
  unsigned long long v0[4], v1[4], v2[4], v3[4];
  f32x4 pm[4];

#define KC_ISSUE(S, jn) do { \
    __builtin_amdgcn_sched_barrier(0); \
    gld_lds16(xqb + (size_t)((jn) + srow) * DD + sch * 8, asb + (S) * 1024); \
    gld_lds16(xqb + (size_t)((jn) + 8 + srow) * DD + sch * 8, asb + (S) * 1024 + 512); \
    __builtin_amdgcn_sched_barrier(0); \
    { const unsigned short* pj = pv0 + (jn); \
      asm volatile("global_load_dwordx2 %0, %1, off" : "=v"(v0[S]) : "v"(pj)); \
      asm volatile("global_load_dwordx2 %0, %1, off" : "=v"(v1[S]) : "v"(pj + 16 * TT)); \
      asm volatile("global_load_dwordx2 %0, %1, off" : "=v"(v2[S]) : "v"(pj + 32 * TT)); \
      asm volatile("global_load_dwordx2 %0, %1, off" : "=v"(v3[S]) : "v"(pj + 48 * TT)); \
      asm volatile("global_load_dwordx4 %0, %1, off" : "=v"(pm[S]) : "v"(mmb + (jn) + 4 * q)); } \
    __builtin_amdgcn_sched_barrier(0); \
  } while (0)
#define KC_WAIT(N) do { \
    asm volatile("s_waitcnt vmcnt(" #N ")" ::: "memory"); \
    __builtin_amdgcn_sched_barrier(0); \
  } while (0)
#define KC_BODY(S) do { \
    const unsigned short* ap = asb + (S) * 1024; \
    bf16x8 a00 = *(const bf16x8*)(ap + c * 64 + o1); \
    bf16x8 a01 = *(const bf16x8*)(ap + c * 64 + o2); \
    union { unsigned long long u; bf16x4 v; } b0_, b1_, b2_, b3_; \
    b0_.u = v0[S]; b1_.u = v1[S]; b2_.u = v2[S]; b3_.u = v3[S]; \
    f32x4 cmm = pm[S]; \
    __builtin_amdgcn_s_setprio(1); \
    _Pragma("unroll") for (int u = 0; u < 2; ++u) { \
      f32x4 z = {0.f, 0.f, 0.f, 0.f}; \
      f32x4 s0 = MFMA32(a00, bq0[u], z, 0, 0, 0); \
      s0 = MFMA32(a01, bq1[u], s0, 0, 0, 0); \
      float w00 = __expf(s0[0] - cmm[0]); \
      float w01 = __expf(s0[1] - cmm[1]); \
      float w02 = __expf(s0[2] - cmm[2]); \
      float w03 = __expf(s0[3] - cmm[3]); \
      union { unsigned int uu[2]; bf16x4 v; } plo; \
      plo.uu[0] = pk2bf(w00, w01); \
      plo.uu[1] = pk2bf(w02, w03); \
      o[u][0] = pv_mfma16(plo.v, b0_.v, o[u][0]); \
      o[u][1] = pv_mfma16(plo.v, b1_.v, o[u][1]); \
      o[u][2] = pv_mfma16(plo.v, b2_.v, o[u][2]); \
      o[u][3] = pv_mfma16(plo.v, b3_.v, o[u][3]); \
    } \
    __builtin_amdgcn_s_setprio(0); \
  } while (0)

  KC_ISSUE(0, jq0);
  KC_ISSUE(1, jq0 + 16);
  KC_ISSUE(2, jq0 + 32);
  for (int g = 0; g < 15; ++g) {
    int jb = jq0 + g * 64;
    KC_ISSUE(3, jb + 48); KC_WAIT(21); KC_BODY(0);
    KC_ISSUE(0, jb + 64); KC_WAIT(21); KC_BODY(1);
    KC_ISSUE(1, jb + 80); KC_WAIT(21); KC_BODY(2);
    KC_ISSUE(2, jb + 96); KC_WAIT(21); KC_BODY(3);
  }
  KC_ISSUE(3, jq0 + 1008); KC_WAIT(21); KC_BODY(0);
  KC_WAIT(14); KC_BODY(1);
  KC_WAIT(7);  KC_BODY(2);
  KC_WAIT(0);  KC_BODY(3);

  // cross-wave O reduce: Olds[w][d 64][pitch 36 fp32], overlays A-slabs
  __syncthreads();
  float* ow = (float*)smem + w * 2304;
#pragma unroll
  for (int u = 0; u < 2; ++u)
#pragma unroll
    for (int nt = 0; nt < 4; ++nt)
      *(f32x4*)(ow + (nt * 16 + c) * 36 + u * 16 + 4 * q) = o[u][nt];
  __syncthreads();
  int t = threadIdx.x, d = t & 63, g = t >> 6;  // g = 0..7 -> 4 i's each
  const float* sbase = (const float*)smem;
  f32x4 sA = {0.f, 0.f, 0.f, 0.f};
#pragma unroll
  for (int w2 = 0; w2 < 8; ++w2)
    sA += *(const f32x4*)(sbase + w2 * 2304 + d * 36 + g * 4);
  *(f32x4*)(out + ((size_t)(b * DD + d)) * TT + i0 + g * 4) = sA;
}

extern "C" void kernel_launch(void* const* d_in, const int* in_sizes, int n_in,
                              void* d_out, int out_size, void* d_ws, size_t ws_size,
                              hipStream_t stream) {
  const float* x = (const float*)d_in[0];
  float* out = (float*)d_out;
  unsigned short* xb = (unsigned short*)d_ws;
  unsigned short* xt = xb + (size_t)NROWS * DD;
  float* m = (float*)(xt + (size_t)NROWS * DD);
  float* mmv = m + NROWS;

  ka_init<<<NROWS / 64, 256, 0, stream>>>(x, xb, xt, m);
  kb_l<<<512, 512, 0, stream>>>(xb, m, mmv);
  kc_out<<<512, 512, 0, stream>>>(xb, xt, mmv, out);
}